// Round 6
// baseline (47.943 us; speedup 1.0000x reference)
//
#include <hip/hip_runtime.h>

// Grouped conv1d over W + roll(+1) along H, bf16 MFMA. Single fused kernel.
// x: (128, 48, 28, 28) f32, channel = g*24+ci
// w: (24, 96, 7) f32, w[ci][o][k], shared across the 2 groups
// out: (128, 192, 28, 28) f32, channel = g*96+o
//
// GEMM per (b, hq, g): M=112 (4 OUTPUT h-rows x 28 W), N=96, K=168 pad 192.
// Block owns OUTPUT rows 4hq..4hq+3 (so each channel's write span is exactly
// 7 full 64B lines -> no partial-line RMW); source rows = (4hq+hl-1) mod 28
// absorb the roll.
// k-axis PERMUTATION (must match between A and B):
//   hw slot = ks*32 + kgrp*8 + j, q = ks*4+kgrp (0..23)
//   q<21: k = q/3, ci = (q%3)*8 + j ; q>=21: zero (enforced on B side only)
//
// R6: B-frags built in-kernel from w (48 L2-hot scalar loads/wave, pre-barrier,
// hidden under x staging). Hot loop: 6 ds_read_b128 + 6 MFMA per M-tile.
// Epilogue: ONE aligned float4 store per M-tile (D-quad j=0..3 = 4 consecutive
// t in one row since m0 % 4 == 0 and 4 | 28).

typedef __attribute__((ext_vector_type(8))) short short8;
typedef __attribute__((ext_vector_type(4))) float float4v;

#define B_     128
#define H_     28
#define W_     28
#define CIN_   24
#define COUT_  96
#define K_     7
#define KSTEPS 6
#define NT_    6
#define MT_    7

// float -> bf16 bits, RNE
static __device__ __forceinline__ unsigned f2bf_u(float f) {
    union { float f; unsigned u; } v; v.f = f;
    return (v.u + 0x7fffu + ((v.u >> 16) & 1u)) >> 16;
}
static __device__ __forceinline__ short f2bf(float f) { return (short)f2bf_u(f); }

__global__ __launch_bounds__(384, 4)
void conv_mfma_kernel(const float* __restrict__ x,
                      const float* __restrict__ w,
                      float* __restrict__ out) {
    const int bid = blockIdx.x;           // 128*7*2 = 1792
    const int g   = bid & 1;
    const int hq  = (bid >> 1) % 7;
    const int b   = bid / 14;
    const int tid = threadIdx.x;

    const int lane = tid & 63;
    const int nt   = tid >> 6;            // wave = N-tile, 0..5
    const int cgrp = lane & 15;
    const int kgrp = lane >> 4;

    // ---- B operand in registers: 6 frags = 24 VGPR, from w (L2-hot).
    // Issued before the staging loop -> latency hidden under x loads.
    const int c_out = nt * 16 + cgrp;     // 0..95 within group
    short8 br[KSTEPS];
#pragma unroll
    for (int ks = 0; ks < KSTEPS; ++ks) {
        const int q = ks * 4 + kgrp;
        if (q < 21) {
            const int k   = (q * 11) >> 5;        // q/3
            const int ci0 = (q - 3 * k) * 8;
#pragma unroll
            for (int j = 0; j < 8; ++j)
                br[ks][j] = f2bf(w[(ci0 + j) * (COUT_ * K_) + c_out * K_ + k]);
        } else {
#pragma unroll
            for (int j = 0; j < 8; ++j) br[ks][j] = 0;  // zero-pad K
        }
    }

    // ---- Stage x as bf16 into xs[hl][p][ci]; p = t+3 padded coord.
    // Source row for output row 4hq+hl is (4hq+hl-1) mod 28.
    __shared__ __align__(16) short xs[4 * 36 * 24];     // 6912 B
    for (int idx = tid; idx < 4 * 12 * 36; idx += 384) {
        const int p  = idx % 36;
        const int t2 = idx / 36;
        const int cp = t2 % 12;           // ci pair
        const int hl = t2 / 12;
        const int ws = p - 3;
        const int rsrc = (4 * hq + hl + 27) % 28;       // = (hd - 1) mod 28
        float v0 = 0.0f, v1 = 0.0f;
        if (ws >= 0 && ws < W_) {
            const size_t base = ((size_t)(b * 48 + g * CIN_ + cp * 2) * H_ + rsrc) * W_ + ws;
            v0 = x[base];
            v1 = x[base + (size_t)H_ * W_];
        }
        ((unsigned*)xs)[(hl * 36 + p) * 12 + cp] = f2bf_u(v0) | (f2bf_u(v1) << 16);
    }
    __syncthreads();

    // Per-lane k-step LDS offsets (A and B share the k permutation)
    int koff[KSTEPS];
#pragma unroll
    for (int ks = 0; ks < KSTEPS; ++ks) {
        const int q   = ks * 4 + kgrp;
        const int k   = (q * 11) >> 5;
        const int ci0 = (q - 3 * k) * 8;
        koff[ks] = k * 24 + ci0;
    }

    float* cbase = out + ((size_t)(b * 192 + g * COUT_ + c_out)) * (H_ * W_);

#pragma unroll
    for (int mt = 0; mt < MT_; ++mt) {
        // A-frag row for this lane: m = mt*16 + cgrp
        const int mA = mt * 16 + cgrp;
        const int hA = mA / 28;
        const int tA = mA - hA * 28;
        const int abase = (hA * 36 + tA) * 24;

        float4v acc = (float4v)(0.0f);
#pragma unroll
        for (int ks = 0; ks < KSTEPS; ++ks) {
            const short8 a = *(const short8*)&xs[abase + koff[ks]];
            acc = __builtin_amdgcn_mfma_f32_16x16x32_bf16(a, br[ks], acc, 0, 0, 0);
        }

        // D-quad j=0..3 -> rows m0..m0+3 = 4 consecutive t in ONE h-row.
        const int m0 = mt * 16 + kgrp * 4;
        const int hl = m0 / 28;
        const int t0 = m0 - hl * 28;
        const int hd = 4 * hq + hl;       // output row (roll absorbed in rsrc)
        float4 v; v.x = acc[0]; v.y = acc[1]; v.z = acc[2]; v.w = acc[3];
        *(float4*)&cbase[hd * W_ + t0] = v;
    }
}

extern "C" void kernel_launch(void* const* d_in, const int* in_sizes, int n_in,
                              void* d_out, int out_size, void* d_ws, size_t ws_size,
                              hipStream_t stream) {
    const float* x = (const float*)d_in[0];
    const float* w = (const float*)d_in[1];
    float* out = (float*)d_out;
    conv_mfma_kernel<<<B_ * 7 * 2, 384, 0, stream>>>(x, w, out);
}

// Round 7
// 28.860 us; speedup vs baseline: 1.6612x; 1.6612x over previous
//
#include <hip/hip_runtime.h>

// Grouped conv1d over W + roll(+1) along H, bf16 MFMA. Persistent blocks.
// x: (128, 48, 28, 28) f32, channel = g*24+ci
// w: (24, 96, 7) f32, w[ci][o][k], shared across the 2 groups
// out: (128, 192, 28, 28) f32, channel = g*96+o
//
// R7: grid = 256 = (b,g) -> 1 block/CU, each block loops 7 hq-tiles with a
// double-buffered stage/compute pipeline (stage-load issue -> compute(t) ->
// vmcnt-wait + ds_write(t+1) -> barrier). W: coalesced float4 -> bf16 LDS
// bounce -> 48 ds_read_u16/lane -> 24 VGPR (R6 lesson: never scatter-read w
// from global per lane). Epilogue: R6's aligned float4 quads (measured ideal
// WRITE_SIZE 75.3MB). Block owns OUTPUT rows 4hq..4hq+3; source rows
// (4hq+hl-1) mod 28 absorb the roll; source rows across tiles are disjoint.
//
// GEMM per tile: M=112 (4 rows x 28), N=96, K=168 pad 192.
// k-axis PERMUTATION (A and B must match):
//   q = ks*4+kgrp (0..23); q<21: k=q/3, ci=(q%3)*8+j ; q>=21: zero (B side)

typedef __attribute__((ext_vector_type(8))) short short8;
typedef __attribute__((ext_vector_type(4))) float float4v;

#define B_     128
#define H_     28
#define W_     28
#define CIN_   24
#define COUT_  96
#define K_     7
#define KSTEPS 6
#define NT_    6
#define MT_    7
#define HW_    784

// float -> bf16 bits, RNE
static __device__ __forceinline__ unsigned f2bf_u(float f) {
    union { float f; unsigned u; } v; v.f = f;
    return (v.u + 0x7fffu + ((v.u >> 16) & 1u)) >> 16;
}

__global__ __launch_bounds__(384, 2)
void conv_mfma_kernel(const float* __restrict__ x,
                      const float* __restrict__ w,
                      float* __restrict__ out) {
    const int bid  = blockIdx.x;          // 256 = b*2 + g
    const int g    = bid & 1;
    const int b    = bid >> 1;
    const int tid  = threadIdx.x;
    const int lane = tid & 63;
    const int nt   = tid >> 6;            // wave = N-tile, 0..5
    const int cgrp = lane & 15;
    const int kgrp = lane >> 4;

    // LDS union: prologue wbf[24][96][7] bf16 (32256B); then xs dbuf 2x6912B.
    __shared__ __align__(16) char smem[32256];
    short* wbf = (short*)smem;
    short* xs0 = (short*)smem;            // [4][36][24] bf16
    short* xs1 = (short*)(smem + 6912);

    // ---- wbf: coalesced w read (16128 floats = 4032 float4), bf16 convert
    for (int i = tid; i < 4032; i += 384) {
        const float4 v = ((const float4*)w)[i];
        const unsigned lo = f2bf_u(v.x) | (f2bf_u(v.y) << 16);
        const unsigned hi = f2bf_u(v.z) | (f2bf_u(v.w) << 16);
        ((uint2*)wbf)[i] = make_uint2(lo, hi);   // same linear order as w
    }
    __syncthreads();

    // ---- B fragments -> 24 VGPR (48 ds_read_u16/lane, once per block)
    const int c_out = nt * 16 + cgrp;     // 0..95 within group
    short8 br[KSTEPS];
#pragma unroll
    for (int ks = 0; ks < KSTEPS; ++ks) {
        const int q = ks * 4 + kgrp;
        if (q < 21) {
            const int k   = (q * 11) >> 5;        // q/3
            const int ci0 = (q - 3 * k) * 8;
#pragma unroll
            for (int j = 0; j < 8; ++j)
                br[ks][j] = wbf[((ci0 + j) * COUT_ + c_out) * K_ + k];
        } else {
#pragma unroll
            for (int j = 0; j < 8; ++j) br[ks][j] = 0;  // zero-pad K
        }
    }
    __syncthreads();   // done reading wbf; xs buffers may overwrite it

    // Per-lane k-step LDS offsets (A side of the shared k permutation)
    int koff[KSTEPS];
#pragma unroll
    for (int ks = 0; ks < KSTEPS; ++ks) {
        const int q   = ks * 4 + kgrp;
        const int k   = (q * 11) >> 5;
        const int ci0 = (q - 3 * k) * 8;
        koff[ks] = k * 24 + ci0;
    }

    float* cbase = out + ((size_t)(b * 192 + g * COUT_ + c_out)) * HW_;

    // ---- staging helpers: 1728 packed dwords per tile, 5 iters/thread
    float v0r[5], v1r[5];
    auto stage_load = [&](int ht) {
#pragma unroll
        for (int it = 0; it < 5; ++it) {
            const int idx = tid + it * 384;
            if (idx < 1728) {
                const int p  = idx % 36;
                const int r  = idx / 36;
                const int cp = r % 12;
                const int hl = r / 12;
                const int ws = p - 3;
                const int rsrc = (4 * ht + hl + 27) % 28;
                float a0 = 0.0f, a1 = 0.0f;
                if (ws >= 0 && ws < W_) {
                    const size_t base =
                        ((size_t)(b * 48 + g * CIN_ + cp * 2) * H_ + rsrc) * W_ + ws;
                    a0 = x[base];
                    a1 = x[base + (size_t)HW_];
                }
                v0r[it] = a0; v1r[it] = a1;
            }
        }
    };
    auto stage_write = [&](short* xs) {
#pragma unroll
        for (int it = 0; it < 5; ++it) {
            const int idx = tid + it * 384;
            if (idx < 1728) {
                const int p  = idx % 36;
                const int r  = idx / 36;
                const int cp = r % 12;
                const int hl = r / 12;
                ((unsigned*)xs)[(hl * 36 + p) * 12 + cp] =
                    f2bf_u(v0r[it]) | (f2bf_u(v1r[it]) << 16);
            }
        }
    };
    auto compute_tile = [&](const short* xs, int ht) {
#pragma unroll
        for (int mt = 0; mt < MT_; ++mt) {
            const int mA = mt * 16 + cgrp;
            const int hA = mA / 28;
            const int tA = mA - hA * 28;
            const int abase = (hA * 36 + tA) * 24;
            float4v acc = (float4v)(0.0f);
#pragma unroll
            for (int ks = 0; ks < KSTEPS; ++ks) {
                const short8 a = *(const short8*)&xs[abase + koff[ks]];
                acc = __builtin_amdgcn_mfma_f32_16x16x32_bf16(a, br[ks], acc, 0, 0, 0);
            }
            // D-quad j=0..3 = 4 consecutive t in one h-row (m0 % 4 == 0, 4|28)
            const int m0 = mt * 16 + kgrp * 4;
            const int hl = m0 / 28;
            const int t0 = m0 - hl * 28;
            const int hd = 4 * ht + hl;
            float4 v; v.x = acc[0]; v.y = acc[1]; v.z = acc[2]; v.w = acc[3];
            *(float4*)&cbase[hd * W_ + t0] = v;
        }
    };

    // ---- pipelined hq loop
    stage_load(0);
    stage_write(xs0);
    __syncthreads();
#pragma unroll
    for (int ht = 0; ht < 7; ++ht) {
        const short* cur = (ht & 1) ? xs1 : xs0;
        short*       nxt = (ht & 1) ? xs0 : xs1;
        if (ht < 6) stage_load(ht + 1);   // issue next tile's global loads
        compute_tile(cur, ht);            // MFMA + stores hide the load latency
        if (ht < 6) stage_write(nxt);     // vmcnt-wait, convert, ds_write
        __syncthreads();
    }
}

extern "C" void kernel_launch(void* const* d_in, const int* in_sizes, int n_in,
                              void* d_out, int out_size, void* d_ws, size_t ws_size,
                              hipStream_t stream) {
    const float* x = (const float*)d_in[0];
    const float* w = (const float*)d_in[1];
    float* out = (float*)d_out;
    conv_mfma_kernel<<<B_ * 2, 384, 0, stream>>>(x, w, out);
}